// Round 9
// baseline (137.310 us; speedup 1.0000x reference)
//
#include <hip/hip_runtime.h>

// R9: R8 pipeline + explicit LDS ordering fences (asm memory clobber) at every
// write->read phase boundary (fixes R8's NaN: compiler hoisted next-stage LDS
// stores above prior-stage LDS loads via type-based alias analysis), and
// reduced peak register pressure (MLP3 double-buffer, staggered TP loads).

typedef short  bf16x8 __attribute__((ext_vector_type(8)));
typedef float  f32x4  __attribute__((ext_vector_type(4)));

#define FENCE() asm volatile("" ::: "memory")

constexpr float BETA  = 1.6791767f;
constexpr float RS128 = 0.088388347648318447f;
constexpr float RS64  = 0.125f;
constexpr float RS32  = 0.176776695296636881f;
constexpr float RSQ3  = 0.577350269189625842f;

enum : int {
  O_nm1 = 0,      O_nm2 = 4096,   O_nm3 = 8192,
  O_em1 = 20480,  O_em2 = 24576,  O_em3 = 28672,
  O_nss = 40960,  O_nsv = 49152,  O_nvv = 53248,  O_nvs = 57344,
  O_ess = 59392,  O_esv = 63488,  O_evv = 65536,  O_evs = 67584,
  O_nss2= 68608,  O_nsv2= 76800,  O_ess2= 78848,  O_esv2= 87040,
  O_nos = 89088,  O_nov = 93184,  O_eos = 94208,  O_eov = 98304,
  W_TOTAL = 99328
};

struct Ptrs {
  const float *src, *dst, *ef, *env, *scal;
  const ushort* wf;
  float *out;
};

struct PrepArgs {
  const float* src[22];
  int K[22], N[22], ofs[22];
  ushort* dst;
};

__device__ __forceinline__ ushort f2b(float x) {
  union { float f; unsigned u; } v; v.f = x;
  unsigned r = v.u + 0x7fffu + ((v.u >> 16) & 1u);
  return (ushort)(r >> 16);
}
__device__ __forceinline__ unsigned pk2(float a, float b) {
  unsigned r;
  asm("v_cvt_pk_bf16_f32 %0, %1, %2" : "=v"(r) : "v"(a), "v"(b));
  return r;
}
__device__ __forceinline__ float plo(unsigned p) {
  union { unsigned u; float f; } v; v.u = p << 16; return v.f;
}
__device__ __forceinline__ float phi(unsigned p) {
  union { unsigned u; float f; } v; v.u = p & 0xffff0000u; return v.f;
}

__global__ __launch_bounds__(256) void prep_kernel(PrepArgs A) {
  const int mat = blockIdx.x;
  const float* __restrict__ src = A.src[mat];
  const int K = A.K[mat], N = A.N[mat], KS = K >> 5;
  ushort* dst = A.dst + A.ofs[mat];
  const int total = (N * K) >> 3;
  for (int gi = threadIdx.x; gi < total; gi += 256) {
    int t = gi / (64 * KS), r = gi - t * 64 * KS;
    int ks = r >> 6, lane = r & 63;
    int cc = lane & 15, gg = lane >> 4;
    int n = t * 16 + cc, k0 = ks * 32 + gg * 8;
    ushort v[8];
#pragma unroll
    for (int j = 0; j < 8; ++j) v[j] = f2b(src[(size_t)(k0 + j) * N + n]);
    *(uint4*)(dst + (size_t)gi * 8) = *(const uint4*)v;
  }
}

template<int N>
__device__ __forceinline__ void lda(const ushort* __restrict__ wb, unsigned lofs, bf16x8* a) {
#pragma unroll
  for (int i = 0; i < N; ++i) a[i] = *(const bf16x8*)(wb + i * 512 + lofs);
}
template<int T, int KS>
__device__ __forceinline__ void mfm(const bf16x8* a, const bf16x8* bf, f32x4* out) {
#pragma unroll
  for (int t = 0; t < T; ++t) {
    f32x4 acc = (f32x4){0, 0, 0, 0};
#pragma unroll
    for (int ks = 0; ks < KS; ++ks)
      acc = __builtin_amdgcn_mfma_f32_16x16x32_bf16(a[t * KS + ks], bf[ks], acc, 0, 0, 0);
    out[t] = acc;
  }
}
template<int T, int KS>
__device__ __forceinline__ void mfmacc(const bf16x8* a, const bf16x8* bf, f32x4* out) {
#pragma unroll
  for (int t = 0; t < T; ++t)
#pragma unroll
    for (int ks = 0; ks < KS; ++ks)
      out[t] = __builtin_amdgcn_mfma_f32_16x16x32_bf16(a[t * KS + ks], bf[ks], out[t], 0, 0, 0);
}

__device__ __forceinline__ void put2(ushort* b, int cg, int col, const f32x4& d) {
  uint2 p; p.x = pk2(d[0], d[1]); p.y = pk2(d[2], d[3]);
  *(uint2*)(b + cg + col) = p;
}
__device__ __forceinline__ bf16x8 getf(const ushort* b, int cg, int col, int g) {
  return *(const bf16x8*)(b + cg + col + 8 * g);
}
__device__ __forceinline__ bf16x8 ldf8(const float* __restrict__ p) {
  float4 a = *(const float4*)p, b4 = *(const float4*)(p + 4);
  union { unsigned u[4]; bf16x8 v; } r;
  r.u[0] = pk2(a.x, a.y); r.u[1] = pk2(a.z, a.w);
  r.u[2] = pk2(b4.x, b4.y); r.u[3] = pk2(b4.z, b4.w);
  return r.v;
}
__device__ __forceinline__ f32x4 silu4(const f32x4& d) {
  f32x4 o;
#pragma unroll
  for (int r = 0; r < 4; ++r) { float z = d[r] * 0.125f; o[r] = BETA * z / (1.f + __expf(-z)); }
  return o;
}
__device__ __forceinline__ void vecwin(const float* __restrict__ p,
                                       float y0, float y1, float y2,
                                       bf16x8& dotf, bf16x8* xvf) {
  float v[24];
#pragma unroll
  for (int q = 0; q < 6; ++q) *(float4*)&v[4 * q] = *(const float4*)(p + 4 * q);
  float dj[8];
#pragma unroll
  for (int j = 0; j < 8; ++j)
    dj[j] = (v[3 * j] * y0 + v[3 * j + 1] * y1 + v[3 * j + 2] * y2) * RSQ3;
  union { unsigned u[4]; bf16x8 w; } t;
#pragma unroll
  for (int q = 0; q < 4; ++q) t.u[q] = pk2(dj[2 * q], dj[2 * q + 1]);
  dotf = t.w;
#pragma unroll
  for (int i = 0; i < 3; ++i) {
#pragma unroll
    for (int q = 0; q < 4; ++q) t.u[q] = pk2(v[6 * q + i], v[6 * q + 3 + i]);
    xvf[i] = t.w;
  }
}

__global__ __launch_bounds__(256, 2) void mp_kernel(Ptrs P) {
  const int tid  = threadIdx.x;
  const int lane = tid & 63, wid = tid >> 6;
  const int c    = lane & 15, g  = lane >> 4;
  const unsigned lofs = lane * 8;
  const int cg   = c * 136;
  const int e    = (blockIdx.x * 4 + wid) * 16 + c;
  const ushort* __restrict__ WF = P.wf;

  __shared__ ushort sb[4][3][16][136];
  ushort* b0 = &sb[wid][0][0][0];
  ushort* b1 = &sb[wid][1][0][0];
  ushort* b2 = &sb[wid][2][0][0];

  const float* __restrict__ rs = P.src + (size_t)e * 160;
  const float* __restrict__ rd = P.dst + (size_t)e * 160;
  const float* __restrict__ re = P.ef  + (size_t)e * 160;
  const float* __restrict__ rq = P.scal + (size_t)e * 64;

  // ---- S1 weight loads first, then inputs needed now ----
  bf16x8 a1n[8], a1e[8];
  lda<8>(WF + O_nm1, lofs, a1n);
  lda<8>(WF + O_em1, lofs, a1e);

  float4 ev = *(const float4*)(P.env + (size_t)e * 4);
  const float ys = ev.x, yv0 = ev.y, yv1 = ev.z, yv2 = ev.w;
  bf16x8 sc[2];
  sc[0] = ldf8(rq + 8 * g);
  sc[1] = ldf8(rq + 32 + 8 * g);

  f32x4 os[4]; f32x4 ov[3][2];
#pragma unroll
  for (int t = 0; t < 4; ++t) os[t] = (f32x4){0, 0, 0, 0};
#pragma unroll
  for (int i = 0; i < 3; ++i)
#pragma unroll
    for (int t = 0; t < 2; ++t) ov[i][t] = (f32x4){0, 0, 0, 0};

  // ---- MLP1 ----
  {
    f32x4 dn[4], de[4];
    mfm<4, 2>(a1n, sc, dn); mfm<4, 2>(a1e, sc, de);
#pragma unroll
    for (int t = 0; t < 4; ++t) put2(b0, cg, 16 * t + 4 * g, silu4(dn[t]));
#pragma unroll
    for (int t = 0; t < 4; ++t) put2(b2, cg, 16 * t + 4 * g, silu4(de[t]));
  }
  FENCE();

  // S2 loads + node TP input streams issued now
  bf16x8 a2n[8], a2e[8];
  lda<8>(WF + O_nm2, lofs, a2n);
  lda<8>(WF + O_em2, lofs, a2e);
  bf16x8 xsf_n[4];
  xsf_n[0] = ldf8(rs + 8 * g);  xsf_n[1] = ldf8(rs + 32 + 8 * g);
  xsf_n[2] = ldf8(rd + 8 * g);  xsf_n[3] = ldf8(rd + 32 + 8 * g);
  bf16x8 dot_n[2], xv_n[6];
  {
    bf16x8 tmp[3];
    vecwin(rs + 64 + 24 * g, yv0, yv1, yv2, dot_n[0], tmp);
    xv_n[0] = tmp[0]; xv_n[2] = tmp[1]; xv_n[4] = tmp[2];
    vecwin(rd + 64 + 24 * g, yv0, yv1, yv2, dot_n[1], tmp);
    xv_n[1] = tmp[0]; xv_n[3] = tmp[1]; xv_n[5] = tmp[2];
  }

  // ---- MLP2 ----
  {
    bf16x8 hn[2] = { getf(b0, cg, 0, g), getf(b0, cg, 32, g) };
    bf16x8 he[2] = { getf(b2, cg, 0, g), getf(b2, cg, 32, g) };
    f32x4 dn[4], de[4];
    mfm<4, 2>(a2n, hn, dn); mfm<4, 2>(a2e, he, de);
#pragma unroll
    for (int t = 0; t < 4; ++t) put2(b1, cg, 16 * t + 4 * g, silu4(dn[t]));
#pragma unroll
    for (int t = 0; t < 4; ++t) put2(b2, cg, 64 + 16 * t + 4 * g, silu4(de[t]));
  }
  FENCE();

  // ---- MLP3: rotating double-buffer of 12 frags ----
  uint2 Wpn[12], Wpe[12];
  {
    bf16x8 aA[12], aB[12];
    lda<12>(WF + O_nm3, lofs, aA);
    lda<12>(WF + O_nm3 + 12 * 512, lofs, aB);
    bf16x8 h2n[2] = { getf(b1, cg, 0, g), getf(b1, cg, 32, g) };
    bf16x8 h2e[2] = { getf(b2, cg, 64, g), getf(b2, cg, 96, g) };
    f32x4 dw[6];
    mfm<6, 2>(aA, h2n, dw);
    lda<12>(WF + O_em3, lofs, aA);
#pragma unroll
    for (int t = 0; t < 6; ++t) { Wpn[t].x = pk2(dw[t][0]*0.125f, dw[t][1]*0.125f); Wpn[t].y = pk2(dw[t][2]*0.125f, dw[t][3]*0.125f); }
    mfm<6, 2>(aB, h2n, dw);
    lda<12>(WF + O_em3 + 12 * 512, lofs, aB);
#pragma unroll
    for (int t = 0; t < 6; ++t) { Wpn[6+t].x = pk2(dw[t][0]*0.125f, dw[t][1]*0.125f); Wpn[6+t].y = pk2(dw[t][2]*0.125f, dw[t][3]*0.125f); }
    mfm<6, 2>(aA, h2e, dw);
#pragma unroll
    for (int t = 0; t < 6; ++t) { Wpe[t].x = pk2(dw[t][0]*0.125f, dw[t][1]*0.125f); Wpe[t].y = pk2(dw[t][2]*0.125f, dw[t][3]*0.125f); }
    mfm<6, 2>(aB, h2e, dw);
#pragma unroll
    for (int t = 0; t < 6; ++t) { Wpe[6+t].x = pk2(dw[t][0]*0.125f, dw[t][1]*0.125f); Wpe[6+t].y = pk2(dw[t][2]*0.125f, dw[t][3]*0.125f); }
  }
  FENCE();   // h2n (b1) read must precede node-TP m_v writes to b1

  // ---- node TP (KA=4, KB=2), staggered loads ----
  f32x4 ga[2];
  {
    bf16x8 assn[16], avvn[8];
    lda<16>(WF + O_nss, lofs, assn);
    lda<8>(WF + O_nvv, lofs, avvn);
    {
      f32x4 d[4];
      mfm<4, 4>(assn, xsf_n, d);
#pragma unroll
      for (int t = 0; t < 4; ++t) {
        f32x4 m;
        m[0] = d[t][0]*ys*RS128*plo(Wpn[t].x); m[1] = d[t][1]*ys*RS128*phi(Wpn[t].x);
        m[2] = d[t][2]*ys*RS128*plo(Wpn[t].y); m[3] = d[t][3]*ys*RS128*phi(Wpn[t].y);
        put2(b0, cg, 16 * t + 4 * g, m);
      }
    }
    bf16x8 asvn[8], avsn[4];
    lda<8>(WF + O_nsv, lofs, asvn);
    lda<4>(WF + O_nvs, lofs, avsn);
    {
      f32x4 d[4];
      mfm<4, 2>(avvn, dot_n, d);
#pragma unroll
      for (int t = 0; t < 4; ++t) {
        f32x4 m;
        m[0] = d[t][0]*RS64*plo(Wpn[4+t].x); m[1] = d[t][1]*RS64*phi(Wpn[4+t].x);
        m[2] = d[t][2]*RS64*plo(Wpn[4+t].y); m[3] = d[t][3]*RS64*phi(Wpn[4+t].y);
        put2(b0, cg, 64 + 16 * t + 4 * g, m);
      }
    }
    mfm<2, 4>(asvn, xsf_n, ga);
#pragma unroll
    for (int i = 0; i < 3; ++i) {
      f32x4 db[2];
      mfm<2, 2>(avsn, xv_n + i * 2, db);
      float yvi = (i == 0) ? yv0 : ((i == 1) ? yv1 : yv2);
      ushort* mb = (i == 2) ? b2 : b1;
      int mbase = (i == 1) ? 64 : 0;
#pragma unroll
      for (int t = 0; t < 2; ++t) {
        f32x4 m;
        m[0] = ga[t][0]*RS128*yvi*plo(Wpn[8+t].x); m[1] = ga[t][1]*RS128*yvi*phi(Wpn[8+t].x);
        m[2] = ga[t][2]*RS128*yvi*plo(Wpn[8+t].y); m[3] = ga[t][3]*RS128*yvi*phi(Wpn[8+t].y);
        put2(mb, cg, mbase + 16 * t + 4 * g, m);
      }
#pragma unroll
      for (int t = 0; t < 2; ++t) {
        f32x4 m;
        m[0] = db[t][0]*ys*RS64*plo(Wpn[10+t].x); m[1] = db[t][1]*ys*RS64*phi(Wpn[10+t].x);
        m[2] = db[t][2]*ys*RS64*plo(Wpn[10+t].y); m[3] = db[t][3]*ys*RS64*phi(Wpn[10+t].y);
        put2(mb, cg, mbase + 32 + 16 * t + 4 * g, m);
      }
    }
  }
  FENCE();

  // ---- node SL + OUT (edge TP inputs issued in between) ----
  bf16x8 xsf_e[2]; bf16x8 dot_e[1], xv_e[3];
  {
    bf16x8 as2n[16], av2n[4];
    lda<16>(WF + O_nss2, lofs, as2n);
    lda<4>(WF + O_nsv2, lofs, av2n);
    xsf_e[0] = ldf8(re + 8 * g); xsf_e[1] = ldf8(re + 32 + 8 * g);
    {
      bf16x8 tmp[3];
      vecwin(re + 64 + 24 * g, yv0, yv1, yv2, dot_e[0], tmp);
      xv_e[0] = tmp[0]; xv_e[1] = tmp[1]; xv_e[2] = tmp[2];
    }
    bf16x8 mpf[4];
#pragma unroll
    for (int ks = 0; ks < 4; ++ks) mpf[ks] = getf(b0, cg, 32 * ks, g);
    bf16x8 mvf[6];
    mvf[0] = getf(b1, cg, 0, g);  mvf[1] = getf(b1, cg, 32, g);
    mvf[2] = getf(b1, cg, 64, g); mvf[3] = getf(b1, cg, 96, g);
    mvf[4] = getf(b2, cg, 0, g);  mvf[5] = getf(b2, cg, 32, g);
    {
      f32x4 d[4];
      mfm<4, 4>(as2n, mpf, d);
#pragma unroll
      for (int t = 0; t < 4; ++t) {
        f32x4 m = { d[t][0]*RS128, d[t][1]*RS128, d[t][2]*RS128, d[t][3]*RS128 };
        put2(b2, cg, 64 + 16 * t + 4 * g, m);
      }
    }
    bf16x8 aosn[8], aovn[2];
    lda<8>(WF + O_nos, lofs, aosn);
    lda<2>(WF + O_nov, lofs, aovn);
#pragma unroll
    for (int i = 0; i < 3; ++i) {
      f32x4 dn2[2];
      mfm<2, 2>(av2n, mvf + 2 * i, dn2);
#pragma unroll
      for (int t = 0; t < 2; ++t) {
        f32x4 m = { dn2[t][0]*RS64, dn2[t][1]*RS64, dn2[t][2]*RS64, dn2[t][3]*RS64 };
        put2(b0, cg, i * 32 + 16 * t + 4 * g, m);
      }
    }
    FENCE();   // ns/nv writes before OUT reads
    bf16x8 nsf[2] = { getf(b2, cg, 64, g), getf(b2, cg, 96, g) };
    mfmacc<4, 2>(aosn, nsf, os);
#pragma unroll
    for (int i = 0; i < 3; ++i) {
      bf16x8 nvf = getf(b0, cg, i * 32, g);
#pragma unroll
      for (int t = 0; t < 2; ++t)
        ov[i][t] = __builtin_amdgcn_mfma_f32_16x16x32_bf16(aovn[t], nvf, ov[i][t], 0, 0, 0);
    }
  }
  FENCE();   // node OUT reads before edge TP writes to b0/b1/b2

  // ---- edge TP (KA=2, KB=1) ----
  {
    bf16x8 asse[8], avve[4], asve[4], avse[2];
    lda<8>(WF + O_ess, lofs, asse);
    lda<4>(WF + O_evv, lofs, avve);
    lda<4>(WF + O_esv, lofs, asve);
    lda<2>(WF + O_evs, lofs, avse);
    {
      f32x4 d[4];
      mfm<4, 2>(asse, xsf_e, d);
#pragma unroll
      for (int t = 0; t < 4; ++t) {
        f32x4 m;
        m[0] = d[t][0]*ys*RS64*plo(Wpe[t].x); m[1] = d[t][1]*ys*RS64*phi(Wpe[t].x);
        m[2] = d[t][2]*ys*RS64*plo(Wpe[t].y); m[3] = d[t][3]*ys*RS64*phi(Wpe[t].y);
        put2(b0, cg, 16 * t + 4 * g, m);
      }
    }
    bf16x8 as2e[16];
    lda<16>(WF + O_ess2, lofs, as2e);
    {
      f32x4 d[4];
      mfm<4, 1>(avve, dot_e, d);
#pragma unroll
      for (int t = 0; t < 4; ++t) {
        f32x4 m;
        m[0] = d[t][0]*RS32*plo(Wpe[4+t].x); m[1] = d[t][1]*RS32*phi(Wpe[4+t].x);
        m[2] = d[t][2]*RS32*plo(Wpe[4+t].y); m[3] = d[t][3]*RS32*phi(Wpe[4+t].y);
        put2(b0, cg, 64 + 16 * t + 4 * g, m);
      }
    }
    mfm<2, 2>(asve, xsf_e, ga);
    bf16x8 av2e[4];
    lda<4>(WF + O_esv2, lofs, av2e);
#pragma unroll
    for (int i = 0; i < 3; ++i) {
      f32x4 db[2];
      mfm<2, 1>(avse, xv_e + i, db);
      float yvi = (i == 0) ? yv0 : ((i == 1) ? yv1 : yv2);
      ushort* mb = (i == 2) ? b2 : b1;
      int mbase = (i == 1) ? 64 : 0;
#pragma unroll
      for (int t = 0; t < 2; ++t) {
        f32x4 m;
        m[0] = ga[t][0]*RS64*yvi*plo(Wpe[8+t].x); m[1] = ga[t][1]*RS64*yvi*phi(Wpe[8+t].x);
        m[2] = ga[t][2]*RS64*yvi*plo(Wpe[8+t].y); m[3] = ga[t][3]*RS64*yvi*phi(Wpe[8+t].y);
        put2(mb, cg, mbase + 16 * t + 4 * g, m);
      }
#pragma unroll
      for (int t = 0; t < 2; ++t) {
        f32x4 m;
        m[0] = db[t][0]*ys*RS32*plo(Wpe[10+t].x); m[1] = db[t][1]*ys*RS32*phi(Wpe[10+t].x);
        m[2] = db[t][2]*ys*RS32*plo(Wpe[10+t].y); m[3] = db[t][3]*ys*RS32*phi(Wpe[10+t].y);
        put2(mb, cg, mbase + 32 + 16 * t + 4 * g, m);
      }
    }
    FENCE();   // edge TP writes before edge SL reads

    // ---- edge SL + OUT ----
    bf16x8 mpf[4];
#pragma unroll
    for (int ks = 0; ks < 4; ++ks) mpf[ks] = getf(b0, cg, 32 * ks, g);
    bf16x8 mvf[6];
    mvf[0] = getf(b1, cg, 0, g);  mvf[1] = getf(b1, cg, 32, g);
    mvf[2] = getf(b1, cg, 64, g); mvf[3] = getf(b1, cg, 96, g);
    mvf[4] = getf(b2, cg, 0, g);  mvf[5] = getf(b2, cg, 32, g);
    {
      f32x4 d[4];
      mfm<4, 4>(as2e, mpf, d);
#pragma unroll
      for (int t = 0; t < 4; ++t) {
        f32x4 m = { d[t][0]*RS128, d[t][1]*RS128, d[t][2]*RS128, d[t][3]*RS128 };
        put2(b2, cg, 64 + 16 * t + 4 * g, m);
      }
    }
    bf16x8 aose[8], aove[2];
    lda<8>(WF + O_eos, lofs, aose);
    lda<2>(WF + O_eov, lofs, aove);
#pragma unroll
    for (int i = 0; i < 3; ++i) {
      f32x4 dn2[2];
      mfm<2, 2>(av2e, mvf + 2 * i, dn2);
#pragma unroll
      for (int t = 0; t < 2; ++t) {
        f32x4 m = { dn2[t][0]*RS64, dn2[t][1]*RS64, dn2[t][2]*RS64, dn2[t][3]*RS64 };
        put2(b0, cg, i * 32 + 16 * t + 4 * g, m);
      }
    }
    FENCE();   // ns/nv writes before OUT reads
    bf16x8 nsf[2] = { getf(b2, cg, 64, g), getf(b2, cg, 96, g) };
    mfmacc<4, 2>(aose, nsf, os);
#pragma unroll
    for (int i = 0; i < 3; ++i) {
      bf16x8 nvf = getf(b0, cg, i * 32, g);
#pragma unroll
      for (int t = 0; t < 2; ++t)
        ov[i][t] = __builtin_amdgcn_mfma_f32_16x16x32_bf16(aove[t], nvf, ov[i][t], 0, 0, 0);
    }
  }

  // ---- store ----
  float* __restrict__ po = P.out + (size_t)e * 160;
#pragma unroll
  for (int t = 0; t < 4; ++t) {
    float4 o = { os[t][0] * RS64, os[t][1] * RS64, os[t][2] * RS64, os[t][3] * RS64 };
    *(float4*)(po + 16 * t + 4 * g) = o;
  }
#pragma unroll
  for (int t = 0; t < 2; ++t) {
    float vv[12];
#pragma unroll
    for (int r = 0; r < 4; ++r)
#pragma unroll
      for (int i = 0; i < 3; ++i) vv[3 * r + i] = ov[i][t][r] * RS32;
    *(float4*)(po + 64 + 48 * t + 12 * g)     = *(float4*)&vv[0];
    *(float4*)(po + 64 + 48 * t + 12 * g + 4) = *(float4*)&vv[4];
    *(float4*)(po + 64 + 48 * t + 12 * g + 8) = *(float4*)&vv[8];
  }
}

extern "C" void kernel_launch(void* const* d_in, const int* in_sizes, int n_in,
                              void* d_out, int out_size, void* d_ws, size_t ws_size,
                              hipStream_t stream) {
  PrepArgs A;
  const int src_idx[22] = {21,22,23, 24,25,26, 5,7,6,8, 9,11,10,12, 13,14, 15,16, 17,18, 19,20};
  const int Ks[22] = {64,64,64, 64,64,64, 128,128,64,64, 64,64,32,32, 128,64, 128,64, 64,32, 64,32};
  const int Ns[22] = {64,64,192, 64,64,192, 64,32,64,32, 64,32,64,32, 64,32, 64,32, 64,32, 64,32};
  const int Os[22] = {O_nm1,O_nm2,O_nm3, O_em1,O_em2,O_em3,
                      O_nss,O_nsv,O_nvv,O_nvs, O_ess,O_esv,O_evv,O_evs,
                      O_nss2,O_nsv2, O_ess2,O_esv2, O_nos,O_nov, O_eos,O_eov};
  for (int i = 0; i < 22; ++i) {
    A.src[i] = (const float*)d_in[src_idx[i]];
    A.K[i] = Ks[i]; A.N[i] = Ns[i]; A.ofs[i] = Os[i];
  }
  A.dst = (ushort*)d_ws;
  prep_kernel<<<dim3(22), dim3(256), 0, stream>>>(A);

  Ptrs P;
  P.src  = (const float*)d_in[0];
  P.dst  = (const float*)d_in[1];
  P.ef   = (const float*)d_in[2];
  P.env  = (const float*)d_in[3];
  P.scal = (const float*)d_in[4];
  P.wf   = (const ushort*)d_ws;
  P.out  = (float*)d_out;

  const int E = in_sizes[0] / 160;  // 131072
  mp_kernel<<<dim3(E / 64), dim3(256), 0, stream>>>(P);
}

// Round 10
// 134.624 us; speedup vs baseline: 1.0199x; 1.0199x over previous
//
#include <hip/hip_runtime.h>

// R10: R9 + raw s_barrier rendezvous before each weight-load cluster.
// 4 waves/block load identical A-fragments; phase-aligning them converts
// 3/4 of the per-wave L2 weight traffic (~194KB/wave, ~46us chip-wide)
// into L1/MSHR hits. Raw s_barrier (no waitcnt drain) keeps the R9
// prefetch pipeline; FENCEs still pin LDS ordering (wave-private LDS).

typedef short  bf16x8 __attribute__((ext_vector_type(8)));
typedef float  f32x4  __attribute__((ext_vector_type(4)));

#define FENCE() asm volatile("" ::: "memory")
#define BAR()   __builtin_amdgcn_s_barrier()

constexpr float BETA  = 1.6791767f;
constexpr float RS128 = 0.088388347648318447f;
constexpr float RS64  = 0.125f;
constexpr float RS32  = 0.176776695296636881f;
constexpr float RSQ3  = 0.577350269189625842f;

enum : int {
  O_nm1 = 0,      O_nm2 = 4096,   O_nm3 = 8192,
  O_em1 = 20480,  O_em2 = 24576,  O_em3 = 28672,
  O_nss = 40960,  O_nsv = 49152,  O_nvv = 53248,  O_nvs = 57344,
  O_ess = 59392,  O_esv = 63488,  O_evv = 65536,  O_evs = 67584,
  O_nss2= 68608,  O_nsv2= 76800,  O_ess2= 78848,  O_esv2= 87040,
  O_nos = 89088,  O_nov = 93184,  O_eos = 94208,  O_eov = 98304,
  W_TOTAL = 99328
};

struct Ptrs {
  const float *src, *dst, *ef, *env, *scal;
  const ushort* wf;
  float *out;
};

struct PrepArgs {
  const float* src[22];
  int K[22], N[22], ofs[22];
  ushort* dst;
};

__device__ __forceinline__ ushort f2b(float x) {
  union { float f; unsigned u; } v; v.f = x;
  unsigned r = v.u + 0x7fffu + ((v.u >> 16) & 1u);
  return (ushort)(r >> 16);
}
__device__ __forceinline__ unsigned pk2(float a, float b) {
  unsigned r;
  asm("v_cvt_pk_bf16_f32 %0, %1, %2" : "=v"(r) : "v"(a), "v"(b));
  return r;
}
__device__ __forceinline__ float plo(unsigned p) {
  union { unsigned u; float f; } v; v.u = p << 16; return v.f;
}
__device__ __forceinline__ float phi(unsigned p) {
  union { unsigned u; float f; } v; v.u = p & 0xffff0000u; return v.f;
}

__global__ __launch_bounds__(256) void prep_kernel(PrepArgs A) {
  const int mat = blockIdx.x;
  const float* __restrict__ src = A.src[mat];
  const int K = A.K[mat], N = A.N[mat], KS = K >> 5;
  ushort* dst = A.dst + A.ofs[mat];
  const int total = (N * K) >> 3;
  for (int gi = threadIdx.x; gi < total; gi += 256) {
    int t = gi / (64 * KS), r = gi - t * 64 * KS;
    int ks = r >> 6, lane = r & 63;
    int cc = lane & 15, gg = lane >> 4;
    int n = t * 16 + cc, k0 = ks * 32 + gg * 8;
    ushort v[8];
#pragma unroll
    for (int j = 0; j < 8; ++j) v[j] = f2b(src[(size_t)(k0 + j) * N + n]);
    *(uint4*)(dst + (size_t)gi * 8) = *(const uint4*)v;
  }
}

template<int N>
__device__ __forceinline__ void lda(const ushort* __restrict__ wb, unsigned lofs, bf16x8* a) {
#pragma unroll
  for (int i = 0; i < N; ++i) a[i] = *(const bf16x8*)(wb + i * 512 + lofs);
}
template<int T, int KS>
__device__ __forceinline__ void mfm(const bf16x8* a, const bf16x8* bf, f32x4* out) {
#pragma unroll
  for (int t = 0; t < T; ++t) {
    f32x4 acc = (f32x4){0, 0, 0, 0};
#pragma unroll
    for (int ks = 0; ks < KS; ++ks)
      acc = __builtin_amdgcn_mfma_f32_16x16x32_bf16(a[t * KS + ks], bf[ks], acc, 0, 0, 0);
    out[t] = acc;
  }
}
template<int T, int KS>
__device__ __forceinline__ void mfmacc(const bf16x8* a, const bf16x8* bf, f32x4* out) {
#pragma unroll
  for (int t = 0; t < T; ++t)
#pragma unroll
    for (int ks = 0; ks < KS; ++ks)
      out[t] = __builtin_amdgcn_mfma_f32_16x16x32_bf16(a[t * KS + ks], bf[ks], out[t], 0, 0, 0);
}

__device__ __forceinline__ void put2(ushort* b, int cg, int col, const f32x4& d) {
  uint2 p; p.x = pk2(d[0], d[1]); p.y = pk2(d[2], d[3]);
  *(uint2*)(b + cg + col) = p;
}
__device__ __forceinline__ bf16x8 getf(const ushort* b, int cg, int col, int g) {
  return *(const bf16x8*)(b + cg + col + 8 * g);
}
__device__ __forceinline__ bf16x8 ldf8(const float* __restrict__ p) {
  float4 a = *(const float4*)p, b4 = *(const float4*)(p + 4);
  union { unsigned u[4]; bf16x8 v; } r;
  r.u[0] = pk2(a.x, a.y); r.u[1] = pk2(a.z, a.w);
  r.u[2] = pk2(b4.x, b4.y); r.u[3] = pk2(b4.z, b4.w);
  return r.v;
}
__device__ __forceinline__ f32x4 silu4(const f32x4& d) {
  f32x4 o;
#pragma unroll
  for (int r = 0; r < 4; ++r) { float z = d[r] * 0.125f; o[r] = BETA * z / (1.f + __expf(-z)); }
  return o;
}
__device__ __forceinline__ void vecwin(const float* __restrict__ p,
                                       float y0, float y1, float y2,
                                       bf16x8& dotf, bf16x8* xvf) {
  float v[24];
#pragma unroll
  for (int q = 0; q < 6; ++q) *(float4*)&v[4 * q] = *(const float4*)(p + 4 * q);
  float dj[8];
#pragma unroll
  for (int j = 0; j < 8; ++j)
    dj[j] = (v[3 * j] * y0 + v[3 * j + 1] * y1 + v[3 * j + 2] * y2) * RSQ3;
  union { unsigned u[4]; bf16x8 w; } t;
#pragma unroll
  for (int q = 0; q < 4; ++q) t.u[q] = pk2(dj[2 * q], dj[2 * q + 1]);
  dotf = t.w;
#pragma unroll
  for (int i = 0; i < 3; ++i) {
#pragma unroll
    for (int q = 0; q < 4; ++q) t.u[q] = pk2(v[6 * q + i], v[6 * q + 3 + i]);
    xvf[i] = t.w;
  }
}

__global__ __launch_bounds__(256, 2) void mp_kernel(Ptrs P) {
  const int tid  = threadIdx.x;
  const int lane = tid & 63, wid = tid >> 6;
  const int c    = lane & 15, g  = lane >> 4;
  const unsigned lofs = lane * 8;
  const int cg   = c * 136;
  const int e    = (blockIdx.x * 4 + wid) * 16 + c;
  const ushort* __restrict__ WF = P.wf;

  __shared__ ushort sb[4][3][16][136];
  ushort* b0 = &sb[wid][0][0][0];
  ushort* b1 = &sb[wid][1][0][0];
  ushort* b2 = &sb[wid][2][0][0];

  const float* __restrict__ rs = P.src + (size_t)e * 160;
  const float* __restrict__ rd = P.dst + (size_t)e * 160;
  const float* __restrict__ re = P.ef  + (size_t)e * 160;
  const float* __restrict__ rq = P.scal + (size_t)e * 64;

  // ---- S1 weight loads first (aligned across waves), then inputs ----
  BAR();
  bf16x8 a1n[8], a1e[8];
  lda<8>(WF + O_nm1, lofs, a1n);
  lda<8>(WF + O_em1, lofs, a1e);

  float4 ev = *(const float4*)(P.env + (size_t)e * 4);
  const float ys = ev.x, yv0 = ev.y, yv1 = ev.z, yv2 = ev.w;
  bf16x8 sc[2];
  sc[0] = ldf8(rq + 8 * g);
  sc[1] = ldf8(rq + 32 + 8 * g);

  f32x4 os[4]; f32x4 ov[3][2];
#pragma unroll
  for (int t = 0; t < 4; ++t) os[t] = (f32x4){0, 0, 0, 0};
#pragma unroll
  for (int i = 0; i < 3; ++i)
#pragma unroll
    for (int t = 0; t < 2; ++t) ov[i][t] = (f32x4){0, 0, 0, 0};

  // ---- MLP1 ----
  {
    f32x4 dn[4], de[4];
    mfm<4, 2>(a1n, sc, dn); mfm<4, 2>(a1e, sc, de);
#pragma unroll
    for (int t = 0; t < 4; ++t) put2(b0, cg, 16 * t + 4 * g, silu4(dn[t]));
#pragma unroll
    for (int t = 0; t < 4; ++t) put2(b2, cg, 16 * t + 4 * g, silu4(de[t]));
  }
  FENCE();

  // S2 loads + node TP input streams issued now
  BAR();
  bf16x8 a2n[8], a2e[8];
  lda<8>(WF + O_nm2, lofs, a2n);
  lda<8>(WF + O_em2, lofs, a2e);
  bf16x8 xsf_n[4];
  xsf_n[0] = ldf8(rs + 8 * g);  xsf_n[1] = ldf8(rs + 32 + 8 * g);
  xsf_n[2] = ldf8(rd + 8 * g);  xsf_n[3] = ldf8(rd + 32 + 8 * g);
  bf16x8 dot_n[2], xv_n[6];
  {
    bf16x8 tmp[3];
    vecwin(rs + 64 + 24 * g, yv0, yv1, yv2, dot_n[0], tmp);
    xv_n[0] = tmp[0]; xv_n[2] = tmp[1]; xv_n[4] = tmp[2];
    vecwin(rd + 64 + 24 * g, yv0, yv1, yv2, dot_n[1], tmp);
    xv_n[1] = tmp[0]; xv_n[3] = tmp[1]; xv_n[5] = tmp[2];
  }

  // ---- MLP2 ----
  {
    bf16x8 hn[2] = { getf(b0, cg, 0, g), getf(b0, cg, 32, g) };
    bf16x8 he[2] = { getf(b2, cg, 0, g), getf(b2, cg, 32, g) };
    f32x4 dn[4], de[4];
    mfm<4, 2>(a2n, hn, dn); mfm<4, 2>(a2e, he, de);
#pragma unroll
    for (int t = 0; t < 4; ++t) put2(b1, cg, 16 * t + 4 * g, silu4(dn[t]));
#pragma unroll
    for (int t = 0; t < 4; ++t) put2(b2, cg, 64 + 16 * t + 4 * g, silu4(de[t]));
  }
  FENCE();

  // ---- MLP3: rotating double-buffer of 12 frags ----
  uint2 Wpn[12], Wpe[12];
  {
    BAR();
    bf16x8 aA[12], aB[12];
    lda<12>(WF + O_nm3, lofs, aA);
    lda<12>(WF + O_nm3 + 12 * 512, lofs, aB);
    bf16x8 h2n[2] = { getf(b1, cg, 0, g), getf(b1, cg, 32, g) };
    bf16x8 h2e[2] = { getf(b2, cg, 64, g), getf(b2, cg, 96, g) };
    f32x4 dw[6];
    mfm<6, 2>(aA, h2n, dw);
    lda<12>(WF + O_em3, lofs, aA);
#pragma unroll
    for (int t = 0; t < 6; ++t) { Wpn[t].x = pk2(dw[t][0]*0.125f, dw[t][1]*0.125f); Wpn[t].y = pk2(dw[t][2]*0.125f, dw[t][3]*0.125f); }
    mfm<6, 2>(aB, h2n, dw);
    lda<12>(WF + O_em3 + 12 * 512, lofs, aB);
#pragma unroll
    for (int t = 0; t < 6; ++t) { Wpn[6+t].x = pk2(dw[t][0]*0.125f, dw[t][1]*0.125f); Wpn[6+t].y = pk2(dw[t][2]*0.125f, dw[t][3]*0.125f); }
    mfm<6, 2>(aA, h2e, dw);
#pragma unroll
    for (int t = 0; t < 6; ++t) { Wpe[t].x = pk2(dw[t][0]*0.125f, dw[t][1]*0.125f); Wpe[t].y = pk2(dw[t][2]*0.125f, dw[t][3]*0.125f); }
    mfm<6, 2>(aB, h2e, dw);
#pragma unroll
    for (int t = 0; t < 6; ++t) { Wpe[6+t].x = pk2(dw[t][0]*0.125f, dw[t][1]*0.125f); Wpe[6+t].y = pk2(dw[t][2]*0.125f, dw[t][3]*0.125f); }
  }
  FENCE();   // h2n (b1) read must precede node-TP m_v writes to b1

  // ---- node TP (KA=4, KB=2), staggered loads ----
  f32x4 ga[2];
  {
    BAR();
    bf16x8 assn[16], avvn[8];
    lda<16>(WF + O_nss, lofs, assn);
    lda<8>(WF + O_nvv, lofs, avvn);
    {
      f32x4 d[4];
      mfm<4, 4>(assn, xsf_n, d);
#pragma unroll
      for (int t = 0; t < 4; ++t) {
        f32x4 m;
        m[0] = d[t][0]*ys*RS128*plo(Wpn[t].x); m[1] = d[t][1]*ys*RS128*phi(Wpn[t].x);
        m[2] = d[t][2]*ys*RS128*plo(Wpn[t].y); m[3] = d[t][3]*ys*RS128*phi(Wpn[t].y);
        put2(b0, cg, 16 * t + 4 * g, m);
      }
    }
    BAR();
    bf16x8 asvn[8], avsn[4];
    lda<8>(WF + O_nsv, lofs, asvn);
    lda<4>(WF + O_nvs, lofs, avsn);
    {
      f32x4 d[4];
      mfm<4, 2>(avvn, dot_n, d);
#pragma unroll
      for (int t = 0; t < 4; ++t) {
        f32x4 m;
        m[0] = d[t][0]*RS64*plo(Wpn[4+t].x); m[1] = d[t][1]*RS64*phi(Wpn[4+t].x);
        m[2] = d[t][2]*RS64*plo(Wpn[4+t].y); m[3] = d[t][3]*RS64*phi(Wpn[4+t].y);
        put2(b0, cg, 64 + 16 * t + 4 * g, m);
      }
    }
    mfm<2, 4>(asvn, xsf_n, ga);
#pragma unroll
    for (int i = 0; i < 3; ++i) {
      f32x4 db[2];
      mfm<2, 2>(avsn, xv_n + i * 2, db);
      float yvi = (i == 0) ? yv0 : ((i == 1) ? yv1 : yv2);
      ushort* mb = (i == 2) ? b2 : b1;
      int mbase = (i == 1) ? 64 : 0;
#pragma unroll
      for (int t = 0; t < 2; ++t) {
        f32x4 m;
        m[0] = ga[t][0]*RS128*yvi*plo(Wpn[8+t].x); m[1] = ga[t][1]*RS128*yvi*phi(Wpn[8+t].x);
        m[2] = ga[t][2]*RS128*yvi*plo(Wpn[8+t].y); m[3] = ga[t][3]*RS128*yvi*phi(Wpn[8+t].y);
        put2(mb, cg, mbase + 16 * t + 4 * g, m);
      }
#pragma unroll
      for (int t = 0; t < 2; ++t) {
        f32x4 m;
        m[0] = db[t][0]*ys*RS64*plo(Wpn[10+t].x); m[1] = db[t][1]*ys*RS64*phi(Wpn[10+t].x);
        m[2] = db[t][2]*ys*RS64*plo(Wpn[10+t].y); m[3] = db[t][3]*ys*RS64*phi(Wpn[10+t].y);
        put2(mb, cg, mbase + 32 + 16 * t + 4 * g, m);
      }
    }
  }
  FENCE();

  // ---- node SL + OUT (edge TP inputs issued in between) ----
  bf16x8 xsf_e[2]; bf16x8 dot_e[1], xv_e[3];
  {
    BAR();
    bf16x8 as2n[16], av2n[4];
    lda<16>(WF + O_nss2, lofs, as2n);
    lda<4>(WF + O_nsv2, lofs, av2n);
    xsf_e[0] = ldf8(re + 8 * g); xsf_e[1] = ldf8(re + 32 + 8 * g);
    {
      bf16x8 tmp[3];
      vecwin(re + 64 + 24 * g, yv0, yv1, yv2, dot_e[0], tmp);
      xv_e[0] = tmp[0]; xv_e[1] = tmp[1]; xv_e[2] = tmp[2];
    }
    bf16x8 mpf[4];
#pragma unroll
    for (int ks = 0; ks < 4; ++ks) mpf[ks] = getf(b0, cg, 32 * ks, g);
    bf16x8 mvf[6];
    mvf[0] = getf(b1, cg, 0, g);  mvf[1] = getf(b1, cg, 32, g);
    mvf[2] = getf(b1, cg, 64, g); mvf[3] = getf(b1, cg, 96, g);
    mvf[4] = getf(b2, cg, 0, g);  mvf[5] = getf(b2, cg, 32, g);
    {
      f32x4 d[4];
      mfm<4, 4>(as2n, mpf, d);
#pragma unroll
      for (int t = 0; t < 4; ++t) {
        f32x4 m = { d[t][0]*RS128, d[t][1]*RS128, d[t][2]*RS128, d[t][3]*RS128 };
        put2(b2, cg, 64 + 16 * t + 4 * g, m);
      }
    }
    BAR();
    bf16x8 aosn[8], aovn[2];
    lda<8>(WF + O_nos, lofs, aosn);
    lda<2>(WF + O_nov, lofs, aovn);
#pragma unroll
    for (int i = 0; i < 3; ++i) {
      f32x4 dn2[2];
      mfm<2, 2>(av2n, mvf + 2 * i, dn2);
#pragma unroll
      for (int t = 0; t < 2; ++t) {
        f32x4 m = { dn2[t][0]*RS64, dn2[t][1]*RS64, dn2[t][2]*RS64, dn2[t][3]*RS64 };
        put2(b0, cg, i * 32 + 16 * t + 4 * g, m);
      }
    }
    FENCE();   // ns/nv writes before OUT reads
    bf16x8 nsf[2] = { getf(b2, cg, 64, g), getf(b2, cg, 96, g) };
    mfmacc<4, 2>(aosn, nsf, os);
#pragma unroll
    for (int i = 0; i < 3; ++i) {
      bf16x8 nvf = getf(b0, cg, i * 32, g);
#pragma unroll
      for (int t = 0; t < 2; ++t)
        ov[i][t] = __builtin_amdgcn_mfma_f32_16x16x32_bf16(aovn[t], nvf, ov[i][t], 0, 0, 0);
    }
  }
  FENCE();   // node OUT reads before edge TP writes to b0/b1/b2

  // ---- edge TP (KA=2, KB=1) ----
  {
    BAR();
    bf16x8 asse[8], avve[4], asve[4], avse[2];
    lda<8>(WF + O_ess, lofs, asse);
    lda<4>(WF + O_evv, lofs, avve);
    lda<4>(WF + O_esv, lofs, asve);
    lda<2>(WF + O_evs, lofs, avse);
    {
      f32x4 d[4];
      mfm<4, 2>(asse, xsf_e, d);
#pragma unroll
      for (int t = 0; t < 4; ++t) {
        f32x4 m;
        m[0] = d[t][0]*ys*RS64*plo(Wpe[t].x); m[1] = d[t][1]*ys*RS64*phi(Wpe[t].x);
        m[2] = d[t][2]*ys*RS64*plo(Wpe[t].y); m[3] = d[t][3]*ys*RS64*phi(Wpe[t].y);
        put2(b0, cg, 16 * t + 4 * g, m);
      }
    }
    BAR();
    bf16x8 as2e[16];
    lda<16>(WF + O_ess2, lofs, as2e);
    {
      f32x4 d[4];
      mfm<4, 1>(avve, dot_e, d);
#pragma unroll
      for (int t = 0; t < 4; ++t) {
        f32x4 m;
        m[0] = d[t][0]*RS32*plo(Wpe[4+t].x); m[1] = d[t][1]*RS32*phi(Wpe[4+t].x);
        m[2] = d[t][2]*RS32*plo(Wpe[4+t].y); m[3] = d[t][3]*RS32*phi(Wpe[4+t].y);
        put2(b0, cg, 64 + 16 * t + 4 * g, m);
      }
    }
    mfm<2, 2>(asve, xsf_e, ga);
    bf16x8 av2e[4];
    lda<4>(WF + O_esv2, lofs, av2e);
#pragma unroll
    for (int i = 0; i < 3; ++i) {
      f32x4 db[2];
      mfm<2, 1>(avse, xv_e + i, db);
      float yvi = (i == 0) ? yv0 : ((i == 1) ? yv1 : yv2);
      ushort* mb = (i == 2) ? b2 : b1;
      int mbase = (i == 1) ? 64 : 0;
#pragma unroll
      for (int t = 0; t < 2; ++t) {
        f32x4 m;
        m[0] = ga[t][0]*RS64*yvi*plo(Wpe[8+t].x); m[1] = ga[t][1]*RS64*yvi*phi(Wpe[8+t].x);
        m[2] = ga[t][2]*RS64*yvi*plo(Wpe[8+t].y); m[3] = ga[t][3]*RS64*yvi*phi(Wpe[8+t].y);
        put2(mb, cg, mbase + 16 * t + 4 * g, m);
      }
#pragma unroll
      for (int t = 0; t < 2; ++t) {
        f32x4 m;
        m[0] = db[t][0]*ys*RS32*plo(Wpe[10+t].x); m[1] = db[t][1]*ys*RS32*phi(Wpe[10+t].x);
        m[2] = db[t][2]*ys*RS32*plo(Wpe[10+t].y); m[3] = db[t][3]*ys*RS32*phi(Wpe[10+t].y);
        put2(mb, cg, mbase + 32 + 16 * t + 4 * g, m);
      }
    }
    FENCE();   // edge TP writes before edge SL reads

    // ---- edge SL + OUT ----
    bf16x8 mpf[4];
#pragma unroll
    for (int ks = 0; ks < 4; ++ks) mpf[ks] = getf(b0, cg, 32 * ks, g);
    bf16x8 mvf[6];
    mvf[0] = getf(b1, cg, 0, g);  mvf[1] = getf(b1, cg, 32, g);
    mvf[2] = getf(b1, cg, 64, g); mvf[3] = getf(b1, cg, 96, g);
    mvf[4] = getf(b2, cg, 0, g);  mvf[5] = getf(b2, cg, 32, g);
    {
      f32x4 d[4];
      mfm<4, 4>(as2e, mpf, d);
#pragma unroll
      for (int t = 0; t < 4; ++t) {
        f32x4 m = { d[t][0]*RS128, d[t][1]*RS128, d[t][2]*RS128, d[t][3]*RS128 };
        put2(b2, cg, 64 + 16 * t + 4 * g, m);
      }
    }
    BAR();
    bf16x8 aose[8], aove[2];
    lda<8>(WF + O_eos, lofs, aose);
    lda<2>(WF + O_eov, lofs, aove);
#pragma unroll
    for (int i = 0; i < 3; ++i) {
      f32x4 dn2[2];
      mfm<2, 2>(av2e, mvf + 2 * i, dn2);
#pragma unroll
      for (int t = 0; t < 2; ++t) {
        f32x4 m = { dn2[t][0]*RS64, dn2[t][1]*RS64, dn2[t][2]*RS64, dn2[t][3]*RS64 };
        put2(b0, cg, i * 32 + 16 * t + 4 * g, m);
      }
    }
    FENCE();   // ns/nv writes before OUT reads
    bf16x8 nsf[2] = { getf(b2, cg, 64, g), getf(b2, cg, 96, g) };
    mfmacc<4, 2>(aose, nsf, os);
#pragma unroll
    for (int i = 0; i < 3; ++i) {
      bf16x8 nvf = getf(b0, cg, i * 32, g);
#pragma unroll
      for (int t = 0; t < 2; ++t)
        ov[i][t] = __builtin_amdgcn_mfma_f32_16x16x32_bf16(aove[t], nvf, ov[i][t], 0, 0, 0);
    }
  }

  // ---- store ----
  float* __restrict__ po = P.out + (size_t)e * 160;
#pragma unroll
  for (int t = 0; t < 4; ++t) {
    float4 o = { os[t][0] * RS64, os[t][1] * RS64, os[t][2] * RS64, os[t][3] * RS64 };
    *(float4*)(po + 16 * t + 4 * g) = o;
  }
#pragma unroll
  for (int t = 0; t < 2; ++t) {
    float vv[12];
#pragma unroll
    for (int r = 0; r < 4; ++r)
#pragma unroll
      for (int i = 0; i < 3; ++i) vv[3 * r + i] = ov[i][t][r] * RS32;
    *(float4*)(po + 64 + 48 * t + 12 * g)     = *(float4*)&vv[0];
    *(float4*)(po + 64 + 48 * t + 12 * g + 4) = *(float4*)&vv[4];
    *(float4*)(po + 64 + 48 * t + 12 * g + 8) = *(float4*)&vv[8];
  }
}

extern "C" void kernel_launch(void* const* d_in, const int* in_sizes, int n_in,
                              void* d_out, int out_size, void* d_ws, size_t ws_size,
                              hipStream_t stream) {
  PrepArgs A;
  const int src_idx[22] = {21,22,23, 24,25,26, 5,7,6,8, 9,11,10,12, 13,14, 15,16, 17,18, 19,20};
  const int Ks[22] = {64,64,64, 64,64,64, 128,128,64,64, 64,64,32,32, 128,64, 128,64, 64,32, 64,32};
  const int Ns[22] = {64,64,192, 64,64,192, 64,32,64,32, 64,32,64,32, 64,32, 64,32, 64,32, 64,32};
  const int Os[22] = {O_nm1,O_nm2,O_nm3, O_em1,O_em2,O_em3,
                      O_nss,O_nsv,O_nvv,O_nvs, O_ess,O_esv,O_evv,O_evs,
                      O_nss2,O_nsv2, O_ess2,O_esv2, O_nos,O_nov, O_eos,O_eov};
  for (int i = 0; i < 22; ++i) {
    A.src[i] = (const float*)d_in[src_idx[i]];
    A.K[i] = Ks[i]; A.N[i] = Ns[i]; A.ofs[i] = Os[i];
  }
  A.dst = (ushort*)d_ws;
  prep_kernel<<<dim3(22), dim3(256), 0, stream>>>(A);

  Ptrs P;
  P.src  = (const float*)d_in[0];
  P.dst  = (const float*)d_in[1];
  P.ef   = (const float*)d_in[2];
  P.env  = (const float*)d_in[3];
  P.scal = (const float*)d_in[4];
  P.wf   = (const ushort*)d_ws;
  P.out  = (float*)d_out;

  const int E = in_sizes[0] / 160;  // 131072
  mp_kernel<<<dim3(E / 64), dim3(256), 0, stream>>>(P);
}